// Round 7
// baseline (101.222 us; speedup 1.0000x reference)
//
#include <hip/hip_runtime.h>

#define B 4
#define F 128    // M
#define E 3000   // K
#define T 6000   // N
#define BN 48    // t-columns per block (125 * 48 = 6000 exact)
#define KSTEP 32
#define NKT 94   // ceil(E/32); k 3000..3007 zero-padded
#define NTT 125  // T / BN
#define ESLOT 40 // padded e-slots per t-row: 80B row stride, 16B-aligned 8-blocks

typedef float f32x4 __attribute__((ext_vector_type(4)));
typedef short bf16x8 __attribute__((ext_vector_type(8)));

static __device__ __forceinline__ unsigned short f32_bf16(float x) {
    unsigned u = __float_as_uint(x);
    u += 0x7FFFu + ((u >> 16) & 1u);   // round-to-nearest-even
    return (unsigned short)(u >> 16);
}

// ---------------------------------------------------------------------------
// Prologue: pack features into MFMA fragment order (bf16), zero-padded in k.
// frag = ((b*NKT + kt)*8 + ft): 64 lanes x 8 bf16. Lane l holds
// row m = ft*16 + (l&15), k = kt*32 + (l>>4)*8 + j (j=0..7) — the canonical
// contiguous-8k layout (same pattern as the guide's ref-checked GEMMs).
// ---------------------------------------------------------------------------
__global__ __launch_bounds__(256) void build_afrag(const float* __restrict__ feat,
                                                   unsigned short* __restrict__ afrag) {
    const int gid = blockIdx.x * 256 + threadIdx.x;
    if (gid >= B * NKT * 8 * 64) return;
    const int lane = gid & 63;
    const int frag = gid >> 6;
    const int ft = frag & 7;
    const int kt = (frag >> 3) % NKT;
    const int b  = frag / (8 * NKT);
    const int m  = ft * 16 + (lane & 15);
    const int k0 = kt * 32 + (lane >> 4) * 8;
    const float* src = feat + ((size_t)b * F + m) * E;
    unsigned short v[8];
#pragma unroll
    for (int j = 0; j < 8; ++j) {
        const int k = k0 + j;
        v[j] = (k < E) ? f32_bf16(src[k]) : (unsigned short)0;
    }
    uint4 pack;
    pack.x = (unsigned)v[0] | ((unsigned)v[1] << 16);
    pack.y = (unsigned)v[2] | ((unsigned)v[3] << 16);
    pack.z = (unsigned)v[4] | ((unsigned)v[5] << 16);
    pack.w = (unsigned)v[6] | ((unsigned)v[7] << 16);
    *reinterpret_cast<uint4*>(afrag + (size_t)frag * 512 + lane * 8) = pack;
}

// ---------------------------------------------------------------------------
// Main kernel: out[b, :, t0:t0+48] = (1/occ) * A(128x3000) @ U(3000x48).
// U streamed once from HBM (t-contiguous float2, coalesced), transposed at
// LDS-WRITE time into a t-major tile ut[48][ESLOT] (bf16 0/1), consumed as
// plain aligned ds_read_b128 B-fragments. Double-buffered LDS, depth-2
// register prefetch (T14), one barrier per K-step.
// ---------------------------------------------------------------------------
__global__ __launch_bounds__(256) void unpool_mfma(const float* __restrict__ unroll,
                                                   const unsigned short* __restrict__ afrag,
                                                   const float* __restrict__ occ,
                                                   float* __restrict__ out) {
    __shared__ unsigned short ut[2][BN * ESLOT];

    const int tb = blockIdx.x;
    const int b  = blockIdx.y;
    const int t0 = tb * BN;
    const int tid  = threadIdx.x;
    const int lane = tid & 63;
    const int w    = tid >> 6;    // wave 0..3: owns f rows 32w..32w+31
    const int lrow = lane & 15;
    const int g    = lane >> 4;   // 0..3

    const float* ub = unroll + (size_t)b * E * T + t0;
    const unsigned short* ab = afrag + (size_t)b * NKT * 8 * 512;

    // Staging map: 768 float2 per K-step tile (32 e-rows x 24 float2 of t).
    int e_l[3], t_l[3];
#pragma unroll
    for (int r = 0; r < 3; ++r) {
        const int f2 = tid + 256 * r;
        e_l[r] = f2 / 24;
        t_l[r] = (f2 % 24) * 2;
    }

    f32x4 acc[2][3] = {};   // [f-subtile][t-subtile], 16x16 each

    // Prologue: stage step 0 into buf0 (direct), issue step-1 loads.
#pragma unroll
    for (int r = 0; r < 3; ++r) {
        const float2 u = *reinterpret_cast<const float2*>(ub + (size_t)e_l[r] * T + t_l[r]);
        ut[0][(t_l[r] + 0) * ESLOT + e_l[r]] = (__float_as_uint(u.x) != 0u) ? 0x3F80u : 0u;
        ut[0][(t_l[r] + 1) * ESLOT + e_l[r]] = (__float_as_uint(u.y) != 0u) ? 0x3F80u : 0u;
    }
    float2 uvA[3], uvB[3];
#pragma unroll
    for (int r = 0; r < 3; ++r)
        uvA[r] = *reinterpret_cast<const float2*>(ub + (size_t)(KSTEP + e_l[r]) * T + t_l[r]);
    __syncthreads();

    // Sub-step S: consume buf CUR; write UVOLD (data S+1) -> buf CUR^1;
    // prefetch UVNEW <- step S+2. A-loads pinned before U-loads so the
    // MFMA's vmcnt leaves the 6 prefetch loads in flight.
#define SUBSTEP(S, CUR, UVOLD, UVNEW)                                                     \
    {                                                                                     \
        const unsigned short* ap = ab + ((size_t)(S) * 8 + 2 * w) * 512 + lane * 8;       \
        const bf16x8 a0 = *reinterpret_cast<const bf16x8*>(ap);                           \
        const bf16x8 a1 = *reinterpret_cast<const bf16x8*>(ap + 512);                     \
        __builtin_amdgcn_sched_barrier(0);                                                \
        if ((S) + 2 < NKT) {                                                              \
            _Pragma("unroll")                                                             \
            for (int r = 0; r < 3; ++r) {                                                 \
                const int e = ((S) + 2) * KSTEP + e_l[r];                                 \
                UVNEW[r] = (e < E)                                                        \
                    ? *reinterpret_cast<const float2*>(ub + (size_t)e * T + t_l[r])       \
                    : make_float2(0.0f, 0.0f);                                            \
            }                                                                             \
        }                                                                                 \
        const bf16x8 b0 = *reinterpret_cast<const bf16x8*>(&ut[CUR][(0 * 16 + lrow) * ESLOT + 8 * g]); \
        const bf16x8 b1 = *reinterpret_cast<const bf16x8*>(&ut[CUR][(1 * 16 + lrow) * ESLOT + 8 * g]); \
        const bf16x8 b2 = *reinterpret_cast<const bf16x8*>(&ut[CUR][(2 * 16 + lrow) * ESLOT + 8 * g]); \
        acc[0][0] = __builtin_amdgcn_mfma_f32_16x16x32_bf16(a0, b0, acc[0][0], 0, 0, 0);  \
        acc[0][1] = __builtin_amdgcn_mfma_f32_16x16x32_bf16(a0, b1, acc[0][1], 0, 0, 0);  \
        acc[0][2] = __builtin_amdgcn_mfma_f32_16x16x32_bf16(a0, b2, acc[0][2], 0, 0, 0);  \
        acc[1][0] = __builtin_amdgcn_mfma_f32_16x16x32_bf16(a1, b0, acc[1][0], 0, 0, 0);  \
        acc[1][1] = __builtin_amdgcn_mfma_f32_16x16x32_bf16(a1, b1, acc[1][1], 0, 0, 0);  \
        acc[1][2] = __builtin_amdgcn_mfma_f32_16x16x32_bf16(a1, b2, acc[1][2], 0, 0, 0);  \
        if ((S) + 1 < NKT) {                                                              \
            _Pragma("unroll")                                                             \
            for (int r = 0; r < 3; ++r) {                                                 \
                ut[(CUR) ^ 1][(t_l[r] + 0) * ESLOT + e_l[r]] = (__float_as_uint(UVOLD[r].x) != 0u) ? 0x3F80u : 0u; \
                ut[(CUR) ^ 1][(t_l[r] + 1) * ESLOT + e_l[r]] = (__float_as_uint(UVOLD[r].y) != 0u) ? 0x3F80u : 0u; \
            }                                                                             \
        }                                                                                 \
        __syncthreads();                                                                  \
    }

    for (int s = 0; s < NKT; s += 2) {
        SUBSTEP(s,     0, uvA, uvB);
        SUBSTEP(s + 1, 1, uvB, uvA);
    }
#undef SUBSTEP

    // Epilogue. C/D layout (m89-verified): col(t) = lane&15, row(f) = g*4 + reg.
    float inv[3];
#pragma unroll
    for (int nt = 0; nt < 3; ++nt)
        inv[nt] = 1.0f / occ[b * T + t0 + nt * 16 + lrow];
    float* ob = out + (size_t)b * F * T;
#pragma unroll
    for (int mt = 0; mt < 2; ++mt) {
#pragma unroll
        for (int nt = 0; nt < 3; ++nt) {
#pragma unroll
            for (int r = 0; r < 4; ++r) {
                const int f = w * 32 + mt * 16 + g * 4 + r;
                const int t = t0 + nt * 16 + lrow;
                __builtin_nontemporal_store(acc[mt][nt][r] * inv[nt], ob + (size_t)f * T + t);
            }
        }
    }
}

// ---------------------------------------------------------------------------
// Dense fallback (only if workspace is too small — slow but exact).
// ---------------------------------------------------------------------------
__global__ void unpool_dense_fallback(const float* __restrict__ features,
                                      const float* __restrict__ unroll,
                                      const float* __restrict__ occ,
                                      float* __restrict__ out) {
    const int b = blockIdx.z;
    const int f = blockIdx.y;
    const int t = blockIdx.x * 64 + threadIdx.x;
    if (t >= T) return;
    const float* frow = features + ((size_t)b * F + f) * E;
    const float* ubp = unroll + (size_t)b * E * T;
    float acc = 0.0f;
    for (int e = 0; e < E; ++e) acc += frow[e] * ubp[(size_t)e * T + t];
    out[((size_t)b * F + f) * T + t] = acc / occ[b * T + t];
}

extern "C" void kernel_launch(void* const* d_in, const int* in_sizes, int n_in,
                              void* d_out, int out_size, void* d_ws, size_t ws_size,
                              hipStream_t stream) {
    const float* features = (const float*)d_in[0];   // (B,F,E) fp32
    const float* unroll   = (const float*)d_in[1];   // (B,E,T) fp32 (binary)
    const float* occ      = (const float*)d_in[2];   // (B,T)   fp32
    float* out = (float*)d_out;                      // (B,F,T) fp32

    const size_t afrag_bytes = (size_t)B * NKT * 8 * 512 * sizeof(unsigned short); // ~3.1 MB
    if (ws_size < afrag_bytes) {
        dim3 g((T + 63) / 64, F, B);
        unpool_dense_fallback<<<g, 64, 0, stream>>>(features, unroll, occ, out);
        return;
    }

    unsigned short* afrag = (unsigned short*)d_ws;

    const int nthr = B * NKT * 8 * 64;  // 192512
    build_afrag<<<(nthr + 255) / 256, 256, 0, stream>>>(features, afrag);

    unpool_mfma<<<dim3(NTT, B), 256, 0, stream>>>(unroll, afrag, occ, out);
}

// Round 8
// 93.371 us; speedup vs baseline: 1.0841x; 1.0841x over previous
//
#include <hip/hip_runtime.h>

#define B 4
#define F 128    // M
#define E 3000   // K
#define T 6000   // N
#define BN 48    // t-columns per block (125 * 48 = 6000 exact)
#define KSTEP 32
#define NKT 94   // ceil(E/32); k 3000..3007 zero-padded
#define NTT 125  // T / BN
#define ESLOT 40 // padded e-slots per t-row: 80B row stride, 16B-aligned 8-blocks

typedef float f32x4 __attribute__((ext_vector_type(4)));
typedef short bf16x8 __attribute__((ext_vector_type(8)));

static __device__ __forceinline__ unsigned short f32_bf16(float x) {
    unsigned u = __float_as_uint(x);
    u += 0x7FFFu + ((u >> 16) & 1u);   // round-to-nearest-even
    return (unsigned short)(u >> 16);
}

// Raw workgroup barrier WITHOUT the vmcnt(0) drain __syncthreads carries.
// LDS ops are drained (cross-wave visibility); global loads into registers
// stay in flight — compiler's per-use counted vmcnt waits handle them (T4).
static __device__ __forceinline__ void wg_barrier_nodrain() {
    __builtin_amdgcn_sched_barrier(0);
    asm volatile("s_waitcnt lgkmcnt(0)" ::: "memory");
    __builtin_amdgcn_s_barrier();
    __builtin_amdgcn_sched_barrier(0);
}

// ---------------------------------------------------------------------------
// Prologue: pack features into MFMA fragment order (bf16), zero-padded in k.
// frag = ((b*NKT + kt)*8 + ft): 64 lanes x 8 bf16. Lane l holds
// row m = ft*16 + (l&15), k = kt*32 + (l>>4)*8 + j (j=0..7).
// ---------------------------------------------------------------------------
__global__ __launch_bounds__(256) void build_afrag(const float* __restrict__ feat,
                                                   unsigned short* __restrict__ afrag) {
    const int gid = blockIdx.x * 256 + threadIdx.x;
    if (gid >= B * NKT * 8 * 64) return;
    const int lane = gid & 63;
    const int frag = gid >> 6;
    const int ft = frag & 7;
    const int kt = (frag >> 3) % NKT;
    const int b  = frag / (8 * NKT);
    const int m  = ft * 16 + (lane & 15);
    const int k0 = kt * 32 + (lane >> 4) * 8;
    const float* src = feat + ((size_t)b * F + m) * E;
    unsigned short v[8];
#pragma unroll
    for (int j = 0; j < 8; ++j) {
        const int k = k0 + j;
        v[j] = (k < E) ? f32_bf16(src[k]) : (unsigned short)0;
    }
    uint4 pack;
    pack.x = (unsigned)v[0] | ((unsigned)v[1] << 16);
    pack.y = (unsigned)v[2] | ((unsigned)v[3] << 16);
    pack.z = (unsigned)v[4] | ((unsigned)v[5] << 16);
    pack.w = (unsigned)v[6] | ((unsigned)v[7] << 16);
    *reinterpret_cast<uint4*>(afrag + (size_t)frag * 512 + lane * 8) = pack;
}

// ---------------------------------------------------------------------------
// Main kernel: out[b, :, t0:t0+48] = (1/occ) * A(128x3000) @ U(3000x48).
// U streamed once from HBM (t-contiguous float2, coalesced), transposed at
// LDS-write time into t-major ut[48][ESLOT] (bf16 0/1), consumed as plain
// aligned ds_read_b128 B-fragments. Double-buffered LDS; depth-2 U prefetch
// + depth-1 A prefetch; raw no-drain barriers keep prefetch loads in flight
// across steps (T4 counted-vmcnt via compiler's per-use waits).
// ---------------------------------------------------------------------------
__global__ __launch_bounds__(256) void unpool_mfma(const float* __restrict__ unroll,
                                                   const unsigned short* __restrict__ afrag,
                                                   const float* __restrict__ occ,
                                                   float* __restrict__ out) {
    __shared__ unsigned short ut[2][BN * ESLOT];

    const int tb = blockIdx.x;
    const int b  = blockIdx.y;
    const int t0 = tb * BN;
    const int tid  = threadIdx.x;
    const int lane = tid & 63;
    const int w    = tid >> 6;    // wave 0..3: owns f rows 32w..32w+31
    const int lrow = lane & 15;
    const int g    = lane >> 4;   // 0..3

    const float* ub = unroll + (size_t)b * E * T + t0;
    const unsigned short* ab = afrag + (size_t)b * NKT * 8 * 512;

    // Staging map: 768 float2 per K-step tile (32 e-rows x 24 float2 of t).
    int e_l[3], t_l[3];
#pragma unroll
    for (int r = 0; r < 3; ++r) {
        const int f2 = tid + 256 * r;
        e_l[r] = f2 / 24;
        t_l[r] = (f2 % 24) * 2;
    }

    f32x4 acc[2][3] = {};   // [f-subtile][t-subtile], 16x16 each

    // Prologue: stage U(0) into buf0 directly; issue A(0) then U(1) loads.
#pragma unroll
    for (int r = 0; r < 3; ++r) {
        const float2 u = *reinterpret_cast<const float2*>(ub + (size_t)e_l[r] * T + t_l[r]);
        ut[0][(t_l[r] + 0) * ESLOT + e_l[r]] = (__float_as_uint(u.x) != 0u) ? 0x3F80u : 0u;
        ut[0][(t_l[r] + 1) * ESLOT + e_l[r]] = (__float_as_uint(u.y) != 0u) ? 0x3F80u : 0u;
    }
    bf16x8 aA0, aA1, aB0, aB1;
    {
        const unsigned short* ap = ab + (size_t)(2 * w) * 512 + lane * 8;
        aA0 = *reinterpret_cast<const bf16x8*>(ap);
        aA1 = *reinterpret_cast<const bf16x8*>(ap + 512);
    }
    float2 uvA[3], uvB[3];
#pragma unroll
    for (int r = 0; r < 3; ++r)
        uvA[r] = *reinterpret_cast<const float2*>(ub + (size_t)(KSTEP + e_l[r]) * T + t_l[r]);
    wg_barrier_nodrain();

    // Step S: consume buf CUR with AOLD=A(S); issue ANEW=A(S+1) then
    // UVNEW=U(S+2); write UVOLD=U(S+1) -> buf CUR^1; raw barrier.
#define SUBSTEP(S, CUR, AOLD0, AOLD1, ANEW0, ANEW1, UVOLD, UVNEW)                         \
    {                                                                                     \
        if ((S) + 1 < NKT) {                                                              \
            const unsigned short* ap = ab + ((size_t)((S) + 1) * 8 + 2 * w) * 512 + lane * 8; \
            ANEW0 = *reinterpret_cast<const bf16x8*>(ap);                                 \
            ANEW1 = *reinterpret_cast<const bf16x8*>(ap + 512);                           \
        }                                                                                 \
        if ((S) + 2 < NKT) {                                                              \
            _Pragma("unroll")                                                             \
            for (int r = 0; r < 3; ++r) {                                                 \
                const int e = ((S) + 2) * KSTEP + e_l[r];                                 \
                UVNEW[r] = (e < E)                                                        \
                    ? *reinterpret_cast<const float2*>(ub + (size_t)e * T + t_l[r])       \
                    : make_float2(0.0f, 0.0f);                                            \
            }                                                                             \
        }                                                                                 \
        const bf16x8 b0 = *reinterpret_cast<const bf16x8*>(&ut[CUR][(0 * 16 + lrow) * ESLOT + 8 * g]); \
        const bf16x8 b1 = *reinterpret_cast<const bf16x8*>(&ut[CUR][(1 * 16 + lrow) * ESLOT + 8 * g]); \
        const bf16x8 b2 = *reinterpret_cast<const bf16x8*>(&ut[CUR][(2 * 16 + lrow) * ESLOT + 8 * g]); \
        acc[0][0] = __builtin_amdgcn_mfma_f32_16x16x32_bf16(AOLD0, b0, acc[0][0], 0, 0, 0); \
        acc[0][1] = __builtin_amdgcn_mfma_f32_16x16x32_bf16(AOLD0, b1, acc[0][1], 0, 0, 0); \
        acc[0][2] = __builtin_amdgcn_mfma_f32_16x16x32_bf16(AOLD0, b2, acc[0][2], 0, 0, 0); \
        acc[1][0] = __builtin_amdgcn_mfma_f32_16x16x32_bf16(AOLD1, b0, acc[1][0], 0, 0, 0); \
        acc[1][1] = __builtin_amdgcn_mfma_f32_16x16x32_bf16(AOLD1, b1, acc[1][1], 0, 0, 0); \
        acc[1][2] = __builtin_amdgcn_mfma_f32_16x16x32_bf16(AOLD1, b2, acc[1][2], 0, 0, 0); \
        if ((S) + 1 < NKT) {                                                              \
            _Pragma("unroll")                                                             \
            for (int r = 0; r < 3; ++r) {                                                 \
                ut[(CUR) ^ 1][(t_l[r] + 0) * ESLOT + e_l[r]] = (__float_as_uint(UVOLD[r].x) != 0u) ? 0x3F80u : 0u; \
                ut[(CUR) ^ 1][(t_l[r] + 1) * ESLOT + e_l[r]] = (__float_as_uint(UVOLD[r].y) != 0u) ? 0x3F80u : 0u; \
            }                                                                             \
        }                                                                                 \
        wg_barrier_nodrain();                                                             \
    }

    for (int s = 0; s < NKT; s += 2) {
        SUBSTEP(s,     0, aA0, aA1, aB0, aB1, uvA, uvB);
        SUBSTEP(s + 1, 1, aB0, aB1, aA0, aA1, uvB, uvA);
    }
#undef SUBSTEP

    // Epilogue. C/D layout (m89-verified): col(t) = lane&15, row(f) = g*4 + reg.
    float inv[3];
#pragma unroll
    for (int nt = 0; nt < 3; ++nt)
        inv[nt] = 1.0f / occ[b * T + t0 + nt * 16 + lrow];
    float* ob = out + (size_t)b * F * T;
#pragma unroll
    for (int mt = 0; mt < 2; ++mt) {
#pragma unroll
        for (int nt = 0; nt < 3; ++nt) {
#pragma unroll
            for (int r = 0; r < 4; ++r) {
                const int f = w * 32 + mt * 16 + g * 4 + r;
                const int t = t0 + nt * 16 + lrow;
                __builtin_nontemporal_store(acc[mt][nt][r] * inv[nt], ob + (size_t)f * T + t);
            }
        }
    }
}

// ---------------------------------------------------------------------------
// Dense fallback (only if workspace is too small — slow but exact).
// ---------------------------------------------------------------------------
__global__ void unpool_dense_fallback(const float* __restrict__ features,
                                      const float* __restrict__ unroll,
                                      const float* __restrict__ occ,
                                      float* __restrict__ out) {
    const int b = blockIdx.z;
    const int f = blockIdx.y;
    const int t = blockIdx.x * 64 + threadIdx.x;
    if (t >= T) return;
    const float* frow = features + ((size_t)b * F + f) * E;
    const float* ubp = unroll + (size_t)b * E * T;
    float acc = 0.0f;
    for (int e = 0; e < E; ++e) acc += frow[e] * ubp[(size_t)e * T + t];
    out[((size_t)b * F + f) * T + t] = acc / occ[b * T + t];
}

extern "C" void kernel_launch(void* const* d_in, const int* in_sizes, int n_in,
                              void* d_out, int out_size, void* d_ws, size_t ws_size,
                              hipStream_t stream) {
    const float* features = (const float*)d_in[0];   // (B,F,E) fp32
    const float* unroll   = (const float*)d_in[1];   // (B,E,T) fp32 (binary)
    const float* occ      = (const float*)d_in[2];   // (B,T)   fp32
    float* out = (float*)d_out;                      // (B,F,T) fp32

    const size_t afrag_bytes = (size_t)B * NKT * 8 * 512 * sizeof(unsigned short); // ~3.1 MB
    if (ws_size < afrag_bytes) {
        dim3 g((T + 63) / 64, F, B);
        unpool_dense_fallback<<<g, 64, 0, stream>>>(features, unroll, occ, out);
        return;
    }

    unsigned short* afrag = (unsigned short*)d_ws;

    const int nthr = B * NKT * 8 * 64;  // 192512
    build_afrag<<<(nthr + 255) / 256, 256, 0, stream>>>(features, afrag);

    unpool_mfma<<<dim3(NTT, B), 256, 0, stream>>>(unroll, afrag, occ, out);
}

// Round 9
// 74.896 us; speedup vs baseline: 1.3515x; 1.2467x over previous
//
#include <hip/hip_runtime.h>

#define B 4
#define F 128    // M
#define E 3000   // K
#define T 6000   // N
#define BN 48    // t-columns per block
#define KSTEP 32
#define NKT 94   // ceil(E/32); k 3000..3007 zero-padded
#define NTT 125  // T / BN
#define ESLOT 40 // padded e-slots per t-row (80B stride: 2-way-only read conflicts)

typedef float f32x4 __attribute__((ext_vector_type(4)));
typedef short bf16x8 __attribute__((ext_vector_type(8)));

static __device__ __forceinline__ unsigned short f32_bf16(float x) {
    unsigned u = __float_as_uint(x);
    u += 0x7FFFu + ((u >> 16) & 1u);
    return (unsigned short)(u >> 16);
}

// ---------------------------------------------------------------------------
// Prologue: pack features into MFMA fragment order (bf16), zero-padded in k.
// Verified in R7/R8: lane l of frag (b,kt,ft) holds row m=ft*16+(l&15),
// k = kt*32 + (l>>4)*8 + j.
// ---------------------------------------------------------------------------
__global__ __launch_bounds__(256) void build_afrag(const float* __restrict__ feat,
                                                   unsigned short* __restrict__ afrag) {
    const int gid = blockIdx.x * 256 + threadIdx.x;
    if (gid >= B * NKT * 8 * 64) return;
    const int lane = gid & 63;
    const int frag = gid >> 6;
    const int ft = frag & 7;
    const int kt = (frag >> 3) % NKT;
    const int b  = frag / (8 * NKT);
    const int m  = ft * 16 + (lane & 15);
    const int k0 = kt * 32 + (lane >> 4) * 8;
    const float* src = feat + ((size_t)b * F + m) * E;
    unsigned short v[8];
#pragma unroll
    for (int j = 0; j < 8; ++j) {
        const int k = k0 + j;
        v[j] = (k < E) ? f32_bf16(src[k]) : (unsigned short)0;
    }
    uint4 pack;
    pack.x = (unsigned)v[0] | ((unsigned)v[1] << 16);
    pack.y = (unsigned)v[2] | ((unsigned)v[3] << 16);
    pack.z = (unsigned)v[4] | ((unsigned)v[5] << 16);
    pack.w = (unsigned)v[6] | ((unsigned)v[7] << 16);
    *reinterpret_cast<uint4*>(afrag + (size_t)frag * 512 + lane * 8) = pack;
}

// ---------------------------------------------------------------------------
// Main kernel: wave-split-K, barrier-free main loop.
// Each wave: private dbuf LDS U-tile (48t x 32e bf16), ~24 K-steps, full
// 128x48 partial in acc[8][3]. Epilogue: 4-round LDS reduce of 4 partials.
// ---------------------------------------------------------------------------
__global__ __launch_bounds__(256, 2) void unpool_mfma_ws(
        const float* __restrict__ unroll,
        const unsigned short* __restrict__ afrag,
        const float* __restrict__ occ,
        float* __restrict__ out) {
    __shared__ unsigned short ut[4][2][BN * ESLOT];  // 30720 B
    __shared__ f32x4 red[2][3][3][64];               // 18432 B

    // m204 bijective XCD-chunk swizzle: adjacent tb land on the same XCD.
    const int nwg  = NTT * B;                        // 500
    const int orig = blockIdx.x + gridDim.x * blockIdx.y;
    const int q = nwg / 8, r = nwg % 8;              // 62, 4
    const int xcd = orig & 7, lin = orig >> 3;
    const int newid = (xcd < r ? xcd * (q + 1) : r * (q + 1) + (xcd - r) * q) + lin;
    const int tb = newid % NTT;
    const int b  = newid / NTT;
    const int t0 = tb * BN;

    const int tid  = threadIdx.x;
    const int lane = tid & 63;
    const int w    = tid >> 6;    // wave id: owns K-slice
    const int lrow = lane & 15;
    const int g    = lane >> 4;

    const float* ub = unroll + (size_t)b * E * T + t0;
    const unsigned short* ab = afrag + (size_t)b * NKT * 8 * 512;
    unsigned short (*myut)[BN * ESLOT] = ut[w];

    // Staging map: 192 float4 per step tile (32 e-rows x 12 float4 of t),
    // 6 per lane. Loop-invariant.
    int e_l[6], t4_l[6];
#pragma unroll
    for (int j = 0; j < 6; ++j) {
        const int idx = lane + 64 * j;
        e_l[j]  = idx / 12;
        t4_l[j] = (idx % 12) * 4;
    }

    // K-slice: waves 0,1 -> 24 steps; waves 2,3 -> 23. (24+24+23+23 = 94)
    const int s0 = w * 23 + (w < 2 ? w : 2);
    const int ns = 23 + (w < 2 ? 1 : 0);

    f32x4 acc[8][3] = {};

#define ULOAD(DST, S)                                                                  \
    { _Pragma("unroll") for (int j = 0; j < 6; ++j) {                                  \
          const int e = (S) * KSTEP + e_l[j];                                          \
          DST[j] = (e < E) ? *reinterpret_cast<const float4*>(ub + (size_t)e * T + t4_l[j]) \
                           : make_float4(0.0f, 0.0f, 0.0f, 0.0f); } }

#define UWRITE(SRC, BUF)                                                               \
    { _Pragma("unroll") for (int j = 0; j < 6; ++j) {                                  \
          unsigned short* p = &myut[BUF][e_l[j]];                                      \
          p[(t4_l[j] + 0) * ESLOT] = (__float_as_uint(SRC[j].x) != 0u) ? 0x3F80u : 0u; \
          p[(t4_l[j] + 1) * ESLOT] = (__float_as_uint(SRC[j].y) != 0u) ? 0x3F80u : 0u; \
          p[(t4_l[j] + 2) * ESLOT] = (__float_as_uint(SRC[j].z) != 0u) ? 0x3F80u : 0u; \
          p[(t4_l[j] + 3) * ESLOT] = (__float_as_uint(SRC[j].w) != 0u) ? 0x3F80u : 0u; } }

    // Step: A(s) loads first (pinned), U(s+2) prefetch, B ds_reads, 24 MFMAs,
    // convert+write U(s+1). No barriers — per-wave deps only.
#define STEP(S, BUF, UVOLD, UVNEW)                                                     \
    {                                                                                  \
        bf16x8 afr[8];                                                                 \
        const unsigned short* ap = ab + (size_t)(S) * 8 * 512 + lane * 8;              \
        _Pragma("unroll") for (int ft = 0; ft < 8; ++ft)                               \
            afr[ft] = *reinterpret_cast<const bf16x8*>(ap + ft * 512);                 \
        __builtin_amdgcn_sched_barrier(0);                                             \
        if ((S) + 2 < s0 + ns) ULOAD(UVNEW, (S) + 2);                                  \
        const bf16x8 bf0 = *reinterpret_cast<const bf16x8*>(&myut[BUF][(0 * 16 + lrow) * ESLOT + 8 * g]); \
        const bf16x8 bf1 = *reinterpret_cast<const bf16x8*>(&myut[BUF][(1 * 16 + lrow) * ESLOT + 8 * g]); \
        const bf16x8 bf2 = *reinterpret_cast<const bf16x8*>(&myut[BUF][(2 * 16 + lrow) * ESLOT + 8 * g]); \
        _Pragma("unroll") for (int ft = 0; ft < 8; ++ft) {                             \
            acc[ft][0] = __builtin_amdgcn_mfma_f32_16x16x32_bf16(afr[ft], bf0, acc[ft][0], 0, 0, 0); \
            acc[ft][1] = __builtin_amdgcn_mfma_f32_16x16x32_bf16(afr[ft], bf1, acc[ft][1], 0, 0, 0); \
            acc[ft][2] = __builtin_amdgcn_mfma_f32_16x16x32_bf16(afr[ft], bf2, acc[ft][2], 0, 0, 0); } \
        if ((S) + 1 < s0 + ns) UWRITE(UVOLD, (BUF) ^ 1);                               \
    }

    // Prologue: stage step s0 into buf0; issue s0+1 loads.
    float4 uvA[6], uvB[6];
    ULOAD(uvA, s0);
    UWRITE(uvA, 0);
    if (ns > 1) ULOAD(uvA, s0 + 1);

    for (int i = 0; i < ns; i += 2) {
        STEP(s0 + i, 0, uvA, uvB);
        if (i + 1 < ns) STEP(s0 + i + 1, 1, uvB, uvA);
    }
#undef STEP
#undef UWRITE
#undef ULOAD

    // Epilogue: combine 4 per-wave partials. 4 rounds x 2 ft-chunks.
    float inv[3];
#pragma unroll
    for (int nt = 0; nt < 3; ++nt)
        inv[nt] = 1.0f / occ[b * T + t0 + nt * 16 + lrow];
    float* ob = out + (size_t)b * F * T;

#pragma unroll
    for (int p = 0; p < 4; ++p) {
        __syncthreads();   // red buffer free (round p-1 consumed)
#pragma unroll
        for (int c = 0; c < 2; ++c) {
            const int ft = 2 * p + c;
            const int fw = 2 * c + (p & 1);     // finalizer wave for this chunk
            if (w != fw) {
                const int slot = (w - fw + 4) % 4 - 1;   // 0..2
#pragma unroll
                for (int nt = 0; nt < 3; ++nt)
                    red[c][slot][nt][lane] = acc[ft][nt];
            }
        }
        __syncthreads();
#pragma unroll
        for (int c = 0; c < 2; ++c) {
            const int ft = 2 * p + c;
            const int fw = 2 * c + (p & 1);
            if (w == fw) {
#pragma unroll
                for (int nt = 0; nt < 3; ++nt) {
                    f32x4 v = acc[ft][nt];
#pragma unroll
                    for (int sI = 0; sI < 3; ++sI) v += red[c][sI][nt][lane];
                    const int t = t0 + nt * 16 + lrow;
#pragma unroll
                    for (int rr = 0; rr < 4; ++rr) {
                        const int f = ft * 16 + g * 4 + rr;
                        __builtin_nontemporal_store(v[rr] * inv[nt], ob + (size_t)f * T + t);
                    }
                }
            }
        }
    }
}

// ---------------------------------------------------------------------------
// Dense fallback (only if workspace is too small — slow but exact).
// ---------------------------------------------------------------------------
__global__ void unpool_dense_fallback(const float* __restrict__ features,
                                      const float* __restrict__ unroll,
                                      const float* __restrict__ occ,
                                      float* __restrict__ out) {
    const int b = blockIdx.z;
    const int f = blockIdx.y;
    const int t = blockIdx.x * 64 + threadIdx.x;
    if (t >= T) return;
    const float* frow = features + ((size_t)b * F + f) * E;
    const float* ubp = unroll + (size_t)b * E * T;
    float acc = 0.0f;
    for (int e = 0; e < E; ++e) acc += frow[e] * ubp[(size_t)e * T + t];
    out[((size_t)b * F + f) * T + t] = acc / occ[b * T + t];
}

extern "C" void kernel_launch(void* const* d_in, const int* in_sizes, int n_in,
                              void* d_out, int out_size, void* d_ws, size_t ws_size,
                              hipStream_t stream) {
    const float* features = (const float*)d_in[0];   // (B,F,E) fp32
    const float* unroll   = (const float*)d_in[1];   // (B,E,T) fp32 (binary)
    const float* occ      = (const float*)d_in[2];   // (B,T)   fp32
    float* out = (float*)d_out;                      // (B,F,T) fp32

    const size_t afrag_bytes = (size_t)B * NKT * 8 * 512 * sizeof(unsigned short); // ~3.1 MB
    if (ws_size < afrag_bytes) {
        dim3 g((T + 63) / 64, F, B);
        unpool_dense_fallback<<<g, 64, 0, stream>>>(features, unroll, occ, out);
        return;
    }

    unsigned short* afrag = (unsigned short*)d_ws;

    const int nthr = B * NKT * 8 * 64;  // 192512
    build_afrag<<<(nthr + 255) / 256, 256, 0, stream>>>(features, afrag);

    unpool_mfma_ws<<<dim3(NTT, B), 256, 0, stream>>>(unroll, afrag, occ, out);
}